// Round 9
// baseline (538.000 us; speedup 1.0000x reference)
//
#include <hip/hip_runtime.h>
#include <hip/hip_bf16.h>
#include <stdint.h>

// Problem constants
#define BB 2
#define LL 1024
#define DMODEL 2048
#define DINNER 4096
#define DSTATE 16
#define DTRANK 128
#define XDBL_LD 256   // x_proj rows padded 160 -> 256
#define CHUNK 64
#define NCH (LL / CHUNK)   // 16

typedef unsigned short ushort;
using short8 = __attribute__((ext_vector_type(8))) short;
using f32x4  = __attribute__((ext_vector_type(4))) float;
using us4    = __attribute__((ext_vector_type(4))) ushort;

__device__ __forceinline__ float bf2f(ushort u) {
    union { uint32_t i; float f; } v; v.i = ((uint32_t)u) << 16; return v.f;
}
__device__ __forceinline__ ushort f2bf(float f) {
    union { float f; uint32_t i; } v; v.f = f;
    uint32_t lsb = (v.i >> 16) & 1u;
    uint32_t r = v.i + 0x7FFFu + lsb;   // RNE
    return (ushort)(r >> 16);
}

// Async global->LDS, 16B per lane (lane-ordered, unpadded LDS dest).
__device__ __forceinline__ void glds16(const ushort* g, ushort* l) {
    __builtin_amdgcn_global_load_lds(
        (const __attribute__((address_space(1))) void*)g,
        (__attribute__((address_space(3))) void*)l,
        16, 0, 0);
}

// ---------------------------------------------------------------------------
// Fused f32->bf16 conversion of all weights/activations + x_proj zero-pad.
// ---------------------------------------------------------------------------
__global__ __launch_bounds__(256) void cvt_all(
    const float4* __restrict__ hidden, const float4* __restrict__ inproj,
    const float4* __restrict__ dtw, const float4* __restrict__ outp,
    const float4* __restrict__ xproj,
    us4* __restrict__ hid_h, us4* __restrict__ inp_h, us4* __restrict__ dtp_h,
    us4* __restrict__ outp_h, us4* __restrict__ xpp)
{
    long i = (long)blockIdx.x * 256 + threadIdx.x;
    const float4* src; us4* dst; long j;
    if (i < 1048576)      { src = hidden; dst = hid_h;  j = i; }
    else if (i < 5242880) { src = inproj; dst = inp_h;  j = i - 1048576; }
    else if (i < 5373952) { src = dtw;    dst = dtp_h;  j = i - 5242880; }
    else if (i < 7471104) { src = outp;   dst = outp_h; j = i - 5373952; }
    else {
        j = i - 7471104; dst = xpp;
        if (j >= 163840) { us4 z = {0, 0, 0, 0}; dst[j] = z; return; }
        src = xproj;
    }
    float4 v = src[j];
    us4 o; o.x = f2bf(v.x); o.y = f2bf(v.y); o.z = f2bf(v.z); o.w = f2bf(v.w);
    dst[j] = o;
}

// ---------------------------------------------------------------------------
// Big-K NT GEMM (for in_proj / out_proj): 128x128 tile, 4 waves of 64x64,
// 16x16x32 bf16 MFMA, BK=64, XOR-swizzled LDS, global_load_lds staging,
// K-split via blockIdx.z, XCD swizzle. Requires K % 64 == 0.
// ---------------------------------------------------------------------------
template <int EPI, bool WF, bool WH>
__global__ __launch_bounds__(256) void gemm_nt(
    const ushort* __restrict__ A, int lda,
    const ushort* __restrict__ Bm, int ldb,
    float* __restrict__ Cf, ushort* __restrict__ Ch, int ldc,
    int K, const float* __restrict__ bias)
{
    __shared__ __align__(16) ushort sA[128 * 64];   // 16 KB
    __shared__ __align__(16) ushort sB[128 * 64];   // 16 KB

    const int tid  = threadIdx.x;
    const int lane = tid & 63;
    const int wave = tid >> 6;
    const int wr = wave >> 1, wc = wave & 1;

    // XCD-aware tile swizzle (n-strip per XCD for B L2 reuse)
    const int NT = gridDim.x, MT = gridDim.y;
    int mt, nt;
    if ((NT & 7) == 0) {
        int lin   = blockIdx.y * NT + blockIdx.x;
        int strip = NT >> 3;
        int xcd   = lin & 7;
        int idx   = lin >> 3;
        nt = xcd * strip + (idx % strip);
        mt = idx / strip;
    } else { mt = blockIdx.y; nt = blockIdx.x; }
    const long m0 = (long)mt * 128;
    const long n0 = (long)nt * 128;

    // K-split offsets
    const long zoff = (long)blockIdx.z;
    A  += zoff * (long)K;
    Bm += zoff * (long)K;
    const long Mrows = (long)MT * 128;
    if (WF) Cf += zoff * Mrows * (long)ldc;
    if (WH) Ch += zoff * Mrows * (long)ldc;

    f32x4 acc[4][4] = {};

    const int lrow = lane & 15;
    const int q    = lane >> 4;

    // staging: thread t stages LDS element offset t*8 (+c*2048 per 32-row
    // group). Logical row sr = t>>3; swizzled global block (t&7)^(sr&7).
    const int sr  = tid >> 3;           // 0..31
    const int scb = (tid & 7) ^ (sr & 7);
    const int sc  = scb << 3;
    const ushort* Ag = A  + (m0 + sr) * (long)lda + sc;
    const ushort* Bg = Bm + (n0 + sr) * (long)ldb + sc;
    ushort* lA = sA + tid * 8;
    ushort* lB = sB + tid * 8;

    for (int k0 = 0; k0 < K; k0 += 64) {
        __syncthreads();                 // previous tile fully consumed
        #pragma unroll
        for (int c = 0; c < 4; ++c) {
            glds16(Ag + (c * 32) * (long)lda + k0, lA + c * 2048);
            glds16(Bg + (c * 32) * (long)ldb + k0, lB + c * 2048);
        }
        __syncthreads();                 // DMA drained

        #pragma unroll
        for (int ks = 0; ks < 2; ++ks) {
            const int off = (((ks * 4 + q) ^ (lrow & 7)) << 3);
            short8 af[4], bf[4];
            #pragma unroll
            for (int i = 0; i < 4; ++i)
                af[i] = *(const short8*)&sA[(wr * 64 + i * 16 + lrow) * 64 + off];
            #pragma unroll
            for (int j = 0; j < 4; ++j)
                bf[j] = *(const short8*)&sB[(wc * 64 + j * 16 + lrow) * 64 + off];

            #pragma unroll
            for (int i = 0; i < 4; ++i)
                #pragma unroll
                for (int j = 0; j < 4; ++j)
                    acc[i][j] = __builtin_amdgcn_mfma_f32_16x16x32_bf16(
                        af[i], bf[j], acc[i][j], 0, 0, 0);
        }
    }

    // C/D mapping: col = lane&15, row = q*4 + reg.
    const int r0 = q * 4;
    const int c0 = lane & 15;
    #pragma unroll
    for (int i = 0; i < 4; ++i) {
        #pragma unroll
        for (int j = 0; j < 4; ++j) {
            long col = n0 + wc * 64 + j * 16 + c0;
            float bv = 0.f;
            if (EPI == 1) bv = bias[col];
            #pragma unroll
            for (int r = 0; r < 4; ++r) {
                long row = m0 + wr * 64 + i * 16 + r0 + r;
                float v = acc[i][j][r];
                if (EPI == 1) {
                    v += bv;
                    v = (v > 20.f) ? v : log1pf(__expf(v));  // softplus
                }
                long idx = row * (long)ldc + col;
                if (WF) Cf[idx] = v;
                if (WH) Ch[idx] = f2bf(v);
            }
        }
    }
}

// ---------------------------------------------------------------------------
// LDS-free skinny-N GEMM (x_dbl): C[M,256] = A[M,K] * B[256,K]^T, K large.
// Wave computes 16 rows x 16 cols; MFMA fragments loaded directly from
// global (per-lane b128: row lane&15, k-slice q*8 — L2-served, no LDS,
// no barriers). Block = 4 waves stacked in m. Grid (N/16, M/64).
// Writes f32 + bf16.
// ---------------------------------------------------------------------------
__global__ __launch_bounds__(256) void gemm_skinny(
    const ushort* __restrict__ A, int lda,
    const ushort* __restrict__ Bm, int ldb,
    float* __restrict__ Cf, ushort* __restrict__ Ch, int ldc, int K)
{
    const int tid  = threadIdx.x;
    const int lane = tid & 63;
    const int w    = tid >> 6;
    const int lrow = lane & 15;
    const int q    = lane >> 4;
    const long m0 = (long)blockIdx.y * 64 + w * 16;
    const long n0 = (long)blockIdx.x * 16;

    const ushort* Ap = A  + (m0 + lrow) * (long)lda + q * 8;
    const ushort* Bp = Bm + (n0 + lrow) * (long)ldb + q * 8;

    f32x4 acc = {};
    for (int k0 = 0; k0 < K; k0 += 128) {
        #pragma unroll
        for (int u = 0; u < 4; ++u) {
            short8 af = *(const short8*)(Ap + k0 + u * 32);
            short8 bf = *(const short8*)(Bp + k0 + u * 32);
            acc = __builtin_amdgcn_mfma_f32_16x16x32_bf16(af, bf, acc, 0, 0, 0);
        }
    }

    #pragma unroll
    for (int r = 0; r < 4; ++r) {
        long idx = (m0 + q * 4 + r) * (long)ldc + n0 + lrow;
        Cf[idx] = acc[r];
        Ch[idx] = f2bf(acc[r]);
    }
}

// ---------------------------------------------------------------------------
// LDS-free small-K GEMM (delta): C[2048,4096] = A[2048,128(ld256)] *
// B[4096,128]^T + bias -> softplus -> bf16. Wave computes 16x64, K=128
// fully unrolled. Grid (4096/64, 2048/64) = 2048 blocks (32 waves/CU).
// ---------------------------------------------------------------------------
__global__ __launch_bounds__(256) void gemm_delta(
    const ushort* __restrict__ A,     // xdblh, lda 256
    const ushort* __restrict__ Bm,    // dt_proj_w bf16, ldb 128
    const float* __restrict__ bias,
    ushort* __restrict__ Ch)          // delta, ldc 4096
{
    const int tid  = threadIdx.x;
    const int lane = tid & 63;
    const int w    = tid >> 6;
    const int lrow = lane & 15;
    const int q    = lane >> 4;
    const long m0 = (long)blockIdx.y * 64 + w * 16;
    const long n0 = (long)blockIdx.x * 64;

    const ushort* Ap = A  + (m0 + lrow) * (long)XDBL_LD + q * 8;
    const ushort* Bp = Bm + (n0 + lrow) * (long)DTRANK + q * 8;

    f32x4 acc[4] = {};
    #pragma unroll
    for (int ks = 0; ks < 4; ++ks) {
        short8 af = *(const short8*)(Ap + ks * 32);
        #pragma unroll
        for (int j = 0; j < 4; ++j) {
            short8 bf = *(const short8*)(Bp + j * 16 * DTRANK + ks * 32);
            acc[j] = __builtin_amdgcn_mfma_f32_16x16x32_bf16(af, bf, acc[j], 0, 0, 0);
        }
    }

    #pragma unroll
    for (int j = 0; j < 4; ++j) {
        long col = n0 + j * 16 + lrow;
        float bv = bias[col];
        #pragma unroll
        for (int r = 0; r < 4; ++r) {
            float v = acc[j][r] + bv;
            v = (v > 20.f) ? v : log1pf(__expf(v));  // softplus
            Ch[(m0 + q * 4 + r) * (long)DINNER + col] = f2bf(v);
        }
    }
}

// ---------------------------------------------------------------------------
// Sum NZ per-split partials; write f32 and optionally bf16.
// ---------------------------------------------------------------------------
template <int NZ, bool WH_>
__global__ __launch_bounds__(256) void reduce_k(
    const float4* __restrict__ parts, long stride4, int n4,
    float4* __restrict__ outF, us4* __restrict__ outH)
{
    int i = blockIdx.x * 256 + threadIdx.x;
    if (i >= n4) return;
    float4 s = parts[i];
    #pragma unroll
    for (int z = 1; z < NZ; ++z) {
        float4 v = parts[(long)z * stride4 + i];
        s.x += v.x; s.y += v.y; s.z += v.z; s.w += v.w;
    }
    if (outF) outF[i] = s;
    if (WH_) {
        us4 o; o.x = f2bf(s.x); o.y = f2bf(s.y); o.z = f2bf(s.z); o.w = f2bf(s.w);
        outH[i] = o;
    }
}

// ---------------------------------------------------------------------------
// Depthwise causal conv(4) + bias + SiLU.
// ---------------------------------------------------------------------------
__global__ __launch_bounds__(256) void conv_silu_kernel(
    const ushort* __restrict__ xz,
    const float* __restrict__ cw,
    const float* __restrict__ cb,
    ushort* __restrict__ xc)
{
    int gid = blockIdx.x * 256 + threadIdx.x;   // over 2048*4096
    int d  = gid & (DINNER - 1);
    int rl = gid >> 12;
    int l  = rl & (LL - 1);
    float acc = cb[d];
    #pragma unroll
    for (int j = 0; j < 4; ++j) {
        int li = l - 3 + j;
        if (li >= 0)
            acc += cw[d * 4 + j] * bf2f(xz[(long)(rl - 3 + j) * 8192 + d]);
    }
    float s = acc / (1.f + __expf(-acc));
    xc[gid] = f2bf(s);
}

// ---------------------------------------------------------------------------
// Chunked selective scan (3 phases).
// ---------------------------------------------------------------------------
__global__ __launch_bounds__(256) void scan_p1(
    const ushort* __restrict__ delta,
    const ushort* __restrict__ xc,
    const float*  __restrict__ xdbl,
    const float*  __restrict__ A_log,
    float* __restrict__ Hbuf,
    float* __restrict__ sumdt_buf)
{
    __shared__ float sB[CHUNK * 16];
    const int tid = threadIdx.x;
    const int k = blockIdx.y, b = blockIdx.z;
    const int d = blockIdx.x * 256 + tid;
    const int row0 = b * LL + k * CHUNK;

    #pragma unroll
    for (int i = 0; i < 4; ++i) {
        int idx = i * 256 + tid;                 // = t*16 + s
        sB[idx] = xdbl[(long)(row0 + (idx >> 4)) * XDBL_LD + DTRANK + (idx & 15)];
    }
    __syncthreads();

    float A[DSTATE];
    const float4* Ap = (const float4*)(A_log + d * DSTATE);
    #pragma unroll
    for (int i = 0; i < 4; ++i) {
        float4 v = Ap[i];
        A[i*4+0] = -__expf(v.x); A[i*4+1] = -__expf(v.y);
        A[i*4+2] = -__expf(v.z); A[i*4+3] = -__expf(v.w);
    }

    float H[DSTATE];
    #pragma unroll
    for (int s = 0; s < DSTATE; ++s) H[s] = 0.f;
    float sumdt = 0.f;

    for (int t = 0; t < CHUNK; ++t) {
        const long row = row0 + t;
        const float dt = bf2f(delta[row * DINNER + d]);
        const float xv = bf2f(xc[row * DINNER + d]);
        const float dx = dt * xv;
        sumdt += dt;
        #pragma unroll
        for (int s = 0; s < DSTATE; ++s) {
            float dA = __expf(dt * A[s]);
            H[s] = H[s] * dA + dx * sB[t * 16 + s];
        }
    }

    const long o = ((long)(b * NCH + k) * DINNER + d) * DSTATE;
    float4* Ho = (float4*)(Hbuf + o);
    #pragma unroll
    for (int i = 0; i < 4; ++i) {
        float4 v; v.x = H[i*4+0]; v.y = H[i*4+1]; v.z = H[i*4+2]; v.w = H[i*4+3];
        Ho[i] = v;
    }
    sumdt_buf[(b * NCH + k) * DINNER + d] = sumdt;
}

__global__ __launch_bounds__(256) void scan_p2(
    const float* __restrict__ A_log,
    const float* __restrict__ sumdt_buf,
    float* __restrict__ Hbuf)
{
    int gid = blockIdx.x * 256 + threadIdx.x;   // 131072 = 2*4096*16
    int b = gid >> 16;
    int rem = gid & 65535;
    int d = rem >> 4, s = rem & 15;
    float A = -__expf(A_log[d * DSTATE + s]);
    float h = 0.f;
    for (int k = 0; k < NCH; ++k) {
        long idx = ((long)(b * NCH + k) * DINNER + d) * DSTATE + s;
        float Hk = Hbuf[idx];
        float sd = sumdt_buf[(b * NCH + k) * DINNER + d];
        Hbuf[idx] = h;
        h = h * __expf(A * sd) + Hk;
    }
}

__global__ __launch_bounds__(256) void scan_p3(
    const ushort* __restrict__ delta,
    const ushort* __restrict__ xc,
    const float*  __restrict__ xdbl,
    const ushort* __restrict__ xz,
    const float*  __restrict__ A_log,
    const float*  __restrict__ Dp,
    const float*  __restrict__ hin,
    ushort* __restrict__ y)
{
    __shared__ float sBC[CHUNK * 32];
    const int tid = threadIdx.x;
    const int k = blockIdx.y, b = blockIdx.z;
    const int d = blockIdx.x * 256 + tid;
    const int row0 = b * LL + k * CHUNK;

    #pragma unroll
    for (int i = 0; i < 8; ++i) {
        int idx = i * 256 + tid;                 // = t*32 + c
        sBC[idx] = xdbl[(long)(row0 + (idx >> 5)) * XDBL_LD + DTRANK + (idx & 31)];
    }
    __syncthreads();

    float A[DSTATE];
    const float4* Ap = (const float4*)(A_log + d * DSTATE);
    #pragma unroll
    for (int i = 0; i < 4; ++i) {
        float4 v = Ap[i];
        A[i*4+0] = -__expf(v.x); A[i*4+1] = -__expf(v.y);
        A[i*4+2] = -__expf(v.z); A[i*4+3] = -__expf(v.w);
    }
    const float Dd = Dp[d];

    float h[DSTATE];
    const float4* Hp = (const float4*)(hin + ((long)(b * NCH + k) * DINNER + d) * DSTATE);
    #pragma unroll
    for (int i = 0; i < 4; ++i) {
        float4 v = Hp[i];
        h[i*4+0] = v.x; h[i*4+1] = v.y; h[i*4+2] = v.z; h[i*4+3] = v.w;
    }

    for (int t = 0; t < CHUNK; ++t) {
        const long row = row0 + t;
        const float dt = bf2f(delta[row * DINNER + d]);
        const float xv = bf2f(xc[row * DINNER + d]);
        const float dx = dt * xv;
        float yt = 0.f;
        #pragma unroll
        for (int s = 0; s < DSTATE; ++s) {
            float dA = __expf(dt * A[s]);
            h[s] = h[s] * dA + dx * sBC[t * 32 + s];
            yt += h[s] * sBC[t * 32 + 16 + s];
        }
        yt += xv * Dd;
        const float zv = bf2f(xz[row * 8192 + DINNER + d]);
        yt *= zv / (1.f + __expf(-zv));
        y[row * DINNER + d] = f2bf(yt);
    }
}

// ---------------------------------------------------------------------------
extern "C" void kernel_launch(void* const* d_in, const int* in_sizes, int n_in,
                              void* d_out, int out_size, void* d_ws, size_t ws_size,
                              hipStream_t stream)
{
    const float* hidden    = (const float*)d_in[0];
    const float* in_proj   = (const float*)d_in[1];
    const float* conv_w    = (const float*)d_in[2];
    const float* conv_b    = (const float*)d_in[3];
    const float* x_proj    = (const float*)d_in[4];
    const float* dt_proj_w = (const float*)d_in[5];
    const float* dt_proj_b = (const float*)d_in[6];
    const float* A_log     = (const float*)d_in[7];
    const float* Dp        = (const float*)d_in[8];
    const float* out_proj  = (const float*)d_in[9];
    float* out = (float*)d_out;

    // Workspace layout (bytes, all 16B aligned)
    char* ws = (char*)d_ws;
    ushort* xz_h    = (ushort*)(ws);                // 32 MiB  (dead after scan_p3)
    ushort* xc      = (ushort*)(ws + 33554432);     // 16 MiB  (dead after scan_p3)
    ushort* xpp     = (ushort*)(ws + 50331648);     // 2 MiB
    float*  xdbl    = (float*)(ws + 52428800);      // 2 MiB   (dead after scan_p3)
    ushort* xdblh   = (ushort*)(ws + 54525952);     // 1 MiB
    ushort* delta_h = (ushort*)(ws + 55574528);     // 16 MiB  (dead after scan_p3)
    ushort* yb      = (ushort*)(ws + 72351744);     // 16 MiB
    ushort* hid_h   = (ushort*)(ws + 89128960);     // 8 MiB
    // 32 MiB multi-use region at 97517568 (time-disjoint):
    //   (a) inp_h bf16 weights (until gemm1)
    //   (b) Hbuf 8 MiB + sumdt 0.5 MiB (scan)
    ushort* inp_h   = (ushort*)(ws + 97517568);
    float*  Hbuf    = (float*)(ws + 97517568);
    float*  sumdt   = (float*)(ws + 105906176);
    ushort* dtp_h   = (ushort*)(ws + 131072000);    // 1 MiB
    ushort* outp_h  = (ushort*)(ws + 132120576);    // 16 MiB
    // out_proj split-4 partials: 4 x 16 MiB aliasing ws[0..64 MiB) (dead)
    float*  parts2  = (float*)(ws);

    const int M = BB * LL;  // 2048

    // 0) all f32 -> bf16 conversions + x_proj pad, one dispatch
    cvt_all<<<30208, 256, 0, stream>>>(
        (const float4*)hidden, (const float4*)in_proj, (const float4*)dt_proj_w,
        (const float4*)out_proj, (const float4*)x_proj,
        (us4*)hid_h, (us4*)inp_h, (us4*)dtp_h, (us4*)outp_h, (us4*)xpp);

    // 1) xz = hidden @ in_proj^T   (2048x8192 bf16)
    gemm_nt<0, false, true><<<dim3(8192 / 128, M / 128), 256, 0, stream>>>(
        hid_h, DMODEL, inp_h, DMODEL, nullptr, xz_h, 8192, DMODEL, nullptr);

    // 2) x_conv = silu(causal_conv(x) + conv_b)
    conv_silu_kernel<<<(M * DINNER) / 256, 256, 0, stream>>>(xz_h, conv_w, conv_b, xc);

    // 3) x_dbl = x_conv @ x_proj_pad^T  (LDS-free skinny, f32+bf16 direct)
    gemm_skinny<<<dim3(XDBL_LD / 16, M / 64), 256, 0, stream>>>(
        xc, DINNER, xpp, DINNER, xdbl, xdblh, XDBL_LD, DINNER);

    // 4) delta = softplus(dt_lo @ dt_proj_w^T + b)  (LDS-free small-K)
    gemm_delta<<<dim3(DINNER / 64, M / 64), 256, 0, stream>>>(
        xdblh, dtp_h, dt_proj_b, delta_h);

    // 5) chunked selective scan + D-skip + silu(z) gating -> y (bf16)
    scan_p1<<<dim3(DINNER / 256, NCH, BB), 256, 0, stream>>>(
        delta_h, xc, xdbl, A_log, Hbuf, sumdt);
    scan_p2<<<(BB * DINNER * DSTATE) / 256, 256, 0, stream>>>(
        A_log, sumdt, Hbuf);
    scan_p3<<<dim3(DINNER / 256, NCH, BB), 256, 0, stream>>>(
        delta_h, xc, xdbl, xz_h, A_log, Dp, Hbuf, yb);

    // 6) out = y @ out_proj^T, K split 4x1024 -> partials -> reduce
    gemm_nt<0, true, false><<<dim3(DMODEL / 128, M / 128, 4), 256, 0, stream>>>(
        yb, DINNER, outp_h, DINNER, parts2, nullptr, DMODEL, DINNER / 4, nullptr);
    reduce_k<4, false><<<(M * DMODEL / 4 + 255) / 256, 256, 0, stream>>>(
        (const float4*)parts2, (long)M * DMODEL / 4, M * DMODEL / 4,
        (float4*)out, nullptr);
}

// Round 10
// 509.508 us; speedup vs baseline: 1.0559x; 1.0559x over previous
//
#include <hip/hip_runtime.h>
#include <hip/hip_bf16.h>
#include <stdint.h>

// Problem constants
#define BB 2
#define LL 1024
#define DMODEL 2048
#define DINNER 4096
#define DSTATE 16
#define DTRANK 128
#define XDBL_LD 256   // x_proj rows padded 160 -> 256
#define CHUNK 64
#define NCH (LL / CHUNK)   // 16

typedef unsigned short ushort;
using short8 = __attribute__((ext_vector_type(8))) short;
using f32x4  = __attribute__((ext_vector_type(4))) float;
using us4    = __attribute__((ext_vector_type(4))) ushort;

__device__ __forceinline__ float bf2f(ushort u) {
    union { uint32_t i; float f; } v; v.i = ((uint32_t)u) << 16; return v.f;
}
__device__ __forceinline__ ushort f2bf(float f) {
    union { float f; uint32_t i; } v; v.f = f;
    uint32_t lsb = (v.i >> 16) & 1u;
    uint32_t r = v.i + 0x7FFFu + lsb;   // RNE
    return (ushort)(r >> 16);
}

// Async global->LDS, 16B per lane (lane-ordered, unpadded LDS dest).
__device__ __forceinline__ void glds16(const ushort* g, ushort* l) {
    __builtin_amdgcn_global_load_lds(
        (const __attribute__((address_space(1))) void*)g,
        (__attribute__((address_space(3))) void*)l,
        16, 0, 0);
}

// ---------------------------------------------------------------------------
// Fused f32->bf16 conversion of all weights/activations + x_proj zero-pad.
// ---------------------------------------------------------------------------
__global__ __launch_bounds__(256) void k_cvt(
    const float4* __restrict__ hidden, const float4* __restrict__ inproj,
    const float4* __restrict__ dtw, const float4* __restrict__ outp,
    const float4* __restrict__ xproj,
    us4* __restrict__ hid_h, us4* __restrict__ inp_h, us4* __restrict__ dtp_h,
    us4* __restrict__ outp_h, us4* __restrict__ xpp)
{
    long i = (long)blockIdx.x * 256 + threadIdx.x;
    const float4* src; us4* dst; long j;
    if (i < 1048576)      { src = hidden; dst = hid_h;  j = i; }
    else if (i < 5242880) { src = inproj; dst = inp_h;  j = i - 1048576; }
    else if (i < 5373952) { src = dtw;    dst = dtp_h;  j = i - 5242880; }
    else if (i < 7471104) { src = outp;   dst = outp_h; j = i - 5373952; }
    else {
        j = i - 7471104; dst = xpp;
        if (j >= 163840) { us4 z = {0, 0, 0, 0}; dst[j] = z; return; }
        src = xproj;
    }
    float4 v = src[j];
    us4 o; o.x = f2bf(v.x); o.y = f2bf(v.y); o.z = f2bf(v.z); o.w = f2bf(v.w);
    dst[j] = o;
}

// ---------------------------------------------------------------------------
// Big-K NT GEMM body: 128x128 tile, 4 waves of 64x64, 16x16x32 bf16 MFMA,
// BK=64, XOR-swizzled LDS, global_load_lds staging, K-split via blockIdx.z,
// XCD swizzle. Requires K % 64 == 0. Stamped into named kernels below.
// ---------------------------------------------------------------------------
template <int EPI, bool WF, bool WH>
__device__ __forceinline__ void gemm_body(
    const ushort* __restrict__ A, int lda,
    const ushort* __restrict__ Bm, int ldb,
    float* __restrict__ Cf, ushort* __restrict__ Ch, int ldc,
    int K, const float* __restrict__ bias)
{
    __shared__ __align__(16) ushort sA[128 * 64];   // 16 KB
    __shared__ __align__(16) ushort sB[128 * 64];   // 16 KB

    const int tid  = threadIdx.x;
    const int lane = tid & 63;
    const int wave = tid >> 6;
    const int wr = wave >> 1, wc = wave & 1;

    // XCD-aware tile swizzle
    const int NT = gridDim.x, MT = gridDim.y;
    int mt, nt;
    if ((NT & 7) == 0) {
        int lin   = blockIdx.y * NT + blockIdx.x;
        int strip = NT >> 3;
        int xcd   = lin & 7;
        int idx   = lin >> 3;
        nt = xcd * strip + (idx % strip);
        mt = idx / strip;
    } else { mt = blockIdx.y; nt = blockIdx.x; }
    const long m0 = (long)mt * 128;
    const long n0 = (long)nt * 128;

    // K-split offsets
    const long zoff = (long)blockIdx.z;
    A  += zoff * (long)K;
    Bm += zoff * (long)K;
    const long Mrows = (long)MT * 128;
    if (WF) Cf += zoff * Mrows * (long)ldc;
    if (WH) Ch += zoff * Mrows * (long)ldc;

    f32x4 acc[4][4] = {};

    const int lrow = lane & 15;
    const int q    = lane >> 4;

    const int sr  = tid >> 3;           // 0..31
    const int scb = (tid & 7) ^ (sr & 7);
    const int sc  = scb << 3;
    const ushort* Ag = A  + (m0 + sr) * (long)lda + sc;
    const ushort* Bg = Bm + (n0 + sr) * (long)ldb + sc;
    ushort* lA = sA + tid * 8;
    ushort* lB = sB + tid * 8;

    for (int k0 = 0; k0 < K; k0 += 64) {
        __syncthreads();
        #pragma unroll
        for (int c = 0; c < 4; ++c) {
            glds16(Ag + (c * 32) * (long)lda + k0, lA + c * 2048);
            glds16(Bg + (c * 32) * (long)ldb + k0, lB + c * 2048);
        }
        __syncthreads();

        #pragma unroll
        for (int ks = 0; ks < 2; ++ks) {
            const int off = (((ks * 4 + q) ^ (lrow & 7)) << 3);
            short8 af[4], bf[4];
            #pragma unroll
            for (int i = 0; i < 4; ++i)
                af[i] = *(const short8*)&sA[(wr * 64 + i * 16 + lrow) * 64 + off];
            #pragma unroll
            for (int j = 0; j < 4; ++j)
                bf[j] = *(const short8*)&sB[(wc * 64 + j * 16 + lrow) * 64 + off];

            #pragma unroll
            for (int i = 0; i < 4; ++i)
                #pragma unroll
                for (int j = 0; j < 4; ++j)
                    acc[i][j] = __builtin_amdgcn_mfma_f32_16x16x32_bf16(
                        af[i], bf[j], acc[i][j], 0, 0, 0);
        }
    }

    // C/D mapping: col = lane&15, row = q*4 + reg.
    const int r0 = q * 4;
    const int c0 = lane & 15;
    #pragma unroll
    for (int i = 0; i < 4; ++i) {
        #pragma unroll
        for (int j = 0; j < 4; ++j) {
            long col = n0 + wc * 64 + j * 16 + c0;
            float bv = 0.f;
            if (EPI == 1) bv = bias[col];
            #pragma unroll
            for (int r = 0; r < 4; ++r) {
                long row = m0 + wr * 64 + i * 16 + r0 + r;
                float v = acc[i][j][r];
                if (EPI == 1) {
                    v += bv;
                    v = (v > 20.f) ? v : log1pf(__expf(v));
                }
                long idx = row * (long)ldc + col;
                if (WF) Cf[idx] = v;
                if (WH) Ch[idx] = f2bf(v);
            }
        }
    }
}

__global__ __launch_bounds__(256) void k_inproj(
    const ushort* A, int lda, const ushort* Bm, int ldb,
    ushort* Ch, int ldc, int K)
{
    gemm_body<0, false, true>(A, lda, Bm, ldb, nullptr, Ch, ldc, K, nullptr);
}

__global__ __launch_bounds__(256) void k_outproj(
    const ushort* A, int lda, const ushort* Bm, int ldb,
    float* Cf, int ldc, int K)
{
    gemm_body<0, true, false>(A, lda, Bm, ldb, Cf, nullptr, ldc, K, nullptr);
}

// ---------------------------------------------------------------------------
// LDS-free skinny-N GEMM (x_dbl), split-K 4 via blockIdx.z -> f32 partials.
// Wave computes 16x16; fragments loaded directly from global (L2-served).
// Grid (N/16, M/64, 4) = 2048 blocks -> 32 waves/CU.
// ---------------------------------------------------------------------------
__global__ __launch_bounds__(256) void k_xdbl(
    const ushort* __restrict__ A, int lda,
    const ushort* __restrict__ Bm, int ldb,
    float* __restrict__ Cf, int ldc, int Kz)
{
    const int tid  = threadIdx.x;
    const int lane = tid & 63;
    const int w    = tid >> 6;
    const int lrow = lane & 15;
    const int q    = lane >> 4;
    const long m0 = (long)blockIdx.y * 64 + w * 16;
    const long n0 = (long)blockIdx.x * 16;
    const long z  = blockIdx.z;

    const ushort* Ap = A  + (m0 + lrow) * (long)lda + z * Kz + q * 8;
    const ushort* Bp = Bm + (n0 + lrow) * (long)ldb + z * Kz + q * 8;

    f32x4 acc = {};
    for (int k0 = 0; k0 < Kz; k0 += 128) {
        #pragma unroll
        for (int u = 0; u < 4; ++u) {
            short8 af = *(const short8*)(Ap + k0 + u * 32);
            short8 bf = *(const short8*)(Bp + k0 + u * 32);
            acc = __builtin_amdgcn_mfma_f32_16x16x32_bf16(af, bf, acc, 0, 0, 0);
        }
    }

    float* Cz = Cf + z * (long)(BB * LL) * ldc;
    #pragma unroll
    for (int r = 0; r < 4; ++r)
        Cz[(m0 + q * 4 + r) * (long)ldc + n0 + lrow] = acc[r];
}

// ---------------------------------------------------------------------------
// LDS-free small-K GEMM (delta): softplus(xdblh @ dt_proj_w^T + b) -> bf16.
// Wave 16x64, K=128 unrolled. Grid (64,32) = 2048 blocks.
// ---------------------------------------------------------------------------
__global__ __launch_bounds__(256) void k_delta(
    const ushort* __restrict__ A,     // xdblh, lda 256
    const ushort* __restrict__ Bm,    // dt_proj_w bf16, ldb 128
    const float* __restrict__ bias,
    ushort* __restrict__ Ch)          // delta, ldc 4096
{
    const int tid  = threadIdx.x;
    const int lane = tid & 63;
    const int w    = tid >> 6;
    const int lrow = lane & 15;
    const int q    = lane >> 4;
    const long m0 = (long)blockIdx.y * 64 + w * 16;
    const long n0 = (long)blockIdx.x * 64;

    const ushort* Ap = A  + (m0 + lrow) * (long)XDBL_LD + q * 8;
    const ushort* Bp = Bm + (n0 + lrow) * (long)DTRANK + q * 8;

    f32x4 acc[4] = {};
    #pragma unroll
    for (int ks = 0; ks < 4; ++ks) {
        short8 af = *(const short8*)(Ap + ks * 32);
        #pragma unroll
        for (int j = 0; j < 4; ++j) {
            short8 bf = *(const short8*)(Bp + j * 16 * DTRANK + ks * 32);
            acc[j] = __builtin_amdgcn_mfma_f32_16x16x32_bf16(af, bf, acc[j], 0, 0, 0);
        }
    }

    #pragma unroll
    for (int j = 0; j < 4; ++j) {
        long col = n0 + j * 16 + lrow;
        float bv = bias[col];
        #pragma unroll
        for (int r = 0; r < 4; ++r) {
            float v = acc[j][r] + bv;
            v = (v > 20.f) ? v : log1pf(__expf(v));
            Ch[(m0 + q * 4 + r) * (long)DINNER + col] = f2bf(v);
        }
    }
}

// ---------------------------------------------------------------------------
// Named split-K reducers.
// ---------------------------------------------------------------------------
__global__ __launch_bounds__(256) void k_xdbl_red(
    const float4* __restrict__ parts, float4* __restrict__ outF,
    us4* __restrict__ outH)
{
    int i = blockIdx.x * 256 + threadIdx.x;   // n4 = 2048*256/4 = 131072
    if (i >= 131072) return;
    float4 s = parts[i];
    #pragma unroll
    for (int z = 1; z < 4; ++z) {
        float4 v = parts[(long)z * 131072 + i];
        s.x += v.x; s.y += v.y; s.z += v.z; s.w += v.w;
    }
    outF[i] = s;
    us4 o; o.x = f2bf(s.x); o.y = f2bf(s.y); o.z = f2bf(s.z); o.w = f2bf(s.w);
    outH[i] = o;
}

__global__ __launch_bounds__(256) void k_out_red(
    const float4* __restrict__ parts, float4* __restrict__ outF)
{
    int i = blockIdx.x * 256 + threadIdx.x;   // n4 = 2048*2048/4 = 1048576
    if (i >= 1048576) return;
    float4 a = parts[i];
    float4 b = parts[1048576L + i];
    a.x += b.x; a.y += b.y; a.z += b.z; a.w += b.w;
    outF[i] = a;
}

// ---------------------------------------------------------------------------
// Depthwise causal conv(4) + bias + SiLU.
// ---------------------------------------------------------------------------
__global__ __launch_bounds__(256) void k_conv(
    const ushort* __restrict__ xz,
    const float* __restrict__ cw,
    const float* __restrict__ cb,
    ushort* __restrict__ xc)
{
    int gid = blockIdx.x * 256 + threadIdx.x;   // over 2048*4096
    int d  = gid & (DINNER - 1);
    int rl = gid >> 12;
    int l  = rl & (LL - 1);
    float acc = cb[d];
    #pragma unroll
    for (int j = 0; j < 4; ++j) {
        int li = l - 3 + j;
        if (li >= 0)
            acc += cw[d * 4 + j] * bf2f(xz[(long)(rl - 3 + j) * 8192 + d]);
    }
    float s = acc / (1.f + __expf(-acc));
    xc[gid] = f2bf(s);
}

// ---------------------------------------------------------------------------
// Chunked selective scan (3 phases).
// ---------------------------------------------------------------------------
__global__ __launch_bounds__(256) void k_scan1(
    const ushort* __restrict__ delta,
    const ushort* __restrict__ xc,
    const float*  __restrict__ xdbl,
    const float*  __restrict__ A_log,
    float* __restrict__ Hbuf,
    float* __restrict__ sumdt_buf)
{
    __shared__ float sB[CHUNK * 16];
    const int tid = threadIdx.x;
    const int k = blockIdx.y, b = blockIdx.z;
    const int d = blockIdx.x * 256 + tid;
    const int row0 = b * LL + k * CHUNK;

    #pragma unroll
    for (int i = 0; i < 4; ++i) {
        int idx = i * 256 + tid;                 // = t*16 + s
        sB[idx] = xdbl[(long)(row0 + (idx >> 4)) * XDBL_LD + DTRANK + (idx & 15)];
    }
    __syncthreads();

    float A[DSTATE];
    const float4* Ap = (const float4*)(A_log + d * DSTATE);
    #pragma unroll
    for (int i = 0; i < 4; ++i) {
        float4 v = Ap[i];
        A[i*4+0] = -__expf(v.x); A[i*4+1] = -__expf(v.y);
        A[i*4+2] = -__expf(v.z); A[i*4+3] = -__expf(v.w);
    }

    float H[DSTATE];
    #pragma unroll
    for (int s = 0; s < DSTATE; ++s) H[s] = 0.f;
    float sumdt = 0.f;

    for (int t = 0; t < CHUNK; ++t) {
        const long row = row0 + t;
        const float dt = bf2f(delta[row * DINNER + d]);
        const float xv = bf2f(xc[row * DINNER + d]);
        const float dx = dt * xv;
        sumdt += dt;
        #pragma unroll
        for (int s = 0; s < DSTATE; ++s) {
            float dA = __expf(dt * A[s]);
            H[s] = H[s] * dA + dx * sB[t * 16 + s];
        }
    }

    const long o = ((long)(b * NCH + k) * DINNER + d) * DSTATE;
    float4* Ho = (float4*)(Hbuf + o);
    #pragma unroll
    for (int i = 0; i < 4; ++i) {
        float4 v; v.x = H[i*4+0]; v.y = H[i*4+1]; v.z = H[i*4+2]; v.w = H[i*4+3];
        Ho[i] = v;
    }
    sumdt_buf[(b * NCH + k) * DINNER + d] = sumdt;
}

__global__ __launch_bounds__(256) void k_scan2(
    const float* __restrict__ A_log,
    const float* __restrict__ sumdt_buf,
    float* __restrict__ Hbuf)
{
    int gid = blockIdx.x * 256 + threadIdx.x;   // 131072 = 2*4096*16
    int b = gid >> 16;
    int rem = gid & 65535;
    int d = rem >> 4, s = rem & 15;
    float A = -__expf(A_log[d * DSTATE + s]);
    float h = 0.f;
    for (int k = 0; k < NCH; ++k) {
        long idx = ((long)(b * NCH + k) * DINNER + d) * DSTATE + s;
        float Hk = Hbuf[idx];
        float sd = sumdt_buf[(b * NCH + k) * DINNER + d];
        Hbuf[idx] = h;
        h = h * __expf(A * sd) + Hk;
    }
}

__global__ __launch_bounds__(256) void k_scan3(
    const ushort* __restrict__ delta,
    const ushort* __restrict__ xc,
    const float*  __restrict__ xdbl,
    const ushort* __restrict__ xz,
    const float*  __restrict__ A_log,
    const float*  __restrict__ Dp,
    const float*  __restrict__ hin,
    ushort* __restrict__ y)
{
    __shared__ float sBC[CHUNK * 32];
    const int tid = threadIdx.x;
    const int k = blockIdx.y, b = blockIdx.z;
    const int d = blockIdx.x * 256 + tid;
    const int row0 = b * LL + k * CHUNK;

    #pragma unroll
    for (int i = 0; i < 8; ++i) {
        int idx = i * 256 + tid;                 // = t*32 + c
        sBC[idx] = xdbl[(long)(row0 + (idx >> 5)) * XDBL_LD + DTRANK + (idx & 31)];
    }
    __syncthreads();

    float A[DSTATE];
    const float4* Ap = (const float4*)(A_log + d * DSTATE);
    #pragma unroll
    for (int i = 0; i < 4; ++i) {
        float4 v = Ap[i];
        A[i*4+0] = -__expf(v.x); A[i*4+1] = -__expf(v.y);
        A[i*4+2] = -__expf(v.z); A[i*4+3] = -__expf(v.w);
    }
    const float Dd = Dp[d];

    float h[DSTATE];
    const float4* Hp = (const float4*)(hin + ((long)(b * NCH + k) * DINNER + d) * DSTATE);
    #pragma unroll
    for (int i = 0; i < 4; ++i) {
        float4 v = Hp[i];
        h[i*4+0] = v.x; h[i*4+1] = v.y; h[i*4+2] = v.z; h[i*4+3] = v.w;
    }

    for (int t = 0; t < CHUNK; ++t) {
        const long row = row0 + t;
        const float dt = bf2f(delta[row * DINNER + d]);
        const float xv = bf2f(xc[row * DINNER + d]);
        const float dx = dt * xv;
        float yt = 0.f;
        #pragma unroll
        for (int s = 0; s < DSTATE; ++s) {
            float dA = __expf(dt * A[s]);
            h[s] = h[s] * dA + dx * sBC[t * 32 + s];
            yt += h[s] * sBC[t * 32 + 16 + s];
        }
        yt += xv * Dd;
        const float zv = bf2f(xz[row * 8192 + DINNER + d]);
        yt *= zv / (1.f + __expf(-zv));
        y[row * DINNER + d] = f2bf(yt);
    }
}

// ---------------------------------------------------------------------------
extern "C" void kernel_launch(void* const* d_in, const int* in_sizes, int n_in,
                              void* d_out, int out_size, void* d_ws, size_t ws_size,
                              hipStream_t stream)
{
    const float* hidden    = (const float*)d_in[0];
    const float* in_proj   = (const float*)d_in[1];
    const float* conv_w    = (const float*)d_in[2];
    const float* conv_b    = (const float*)d_in[3];
    const float* x_proj    = (const float*)d_in[4];
    const float* dt_proj_w = (const float*)d_in[5];
    const float* dt_proj_b = (const float*)d_in[6];
    const float* A_log     = (const float*)d_in[7];
    const float* Dp        = (const float*)d_in[8];
    const float* out_proj  = (const float*)d_in[9];
    float* out = (float*)d_out;

    // Workspace layout (bytes, all 16B aligned)
    char* ws = (char*)d_ws;
    ushort* xz_h    = (ushort*)(ws);                // 32 MiB (dead after k_scan3)
    ushort* xc      = (ushort*)(ws + 33554432);     // 16 MiB (dead after k_scan3)
    ushort* xpp     = (ushort*)(ws + 50331648);     // 2 MiB
    float*  xdbl    = (float*)(ws + 52428800);      // 2 MiB  (dead after k_scan3)
    ushort* xdblh   = (ushort*)(ws + 54525952);     // 1 MiB
    ushort* delta_h = (ushort*)(ws + 55574528);     // 16 MiB (dead after k_scan3)
    ushort* yb      = (ushort*)(ws + 72351744);     // 16 MiB
    ushort* hid_h   = (ushort*)(ws + 89128960);     // 8 MiB
    // 32 MiB multi-use region at 97517568 (time-disjoint):
    //   (a) inp_h bf16 weights (until k_inproj)
    //   (b) xdbl split-4 partials 4 x 2 MiB (k_xdbl -> k_xdbl_red)
    //   (c) Hbuf 8 MiB + sumdt 0.5 MiB (scan)
    ushort* inp_h   = (ushort*)(ws + 97517568);
    float*  parts   = (float*)(ws + 97517568);
    float*  Hbuf    = (float*)(ws + 97517568);
    float*  sumdt   = (float*)(ws + 105906176);
    ushort* dtp_h   = (ushort*)(ws + 131072000);    // 1 MiB
    ushort* outp_h  = (ushort*)(ws + 132120576);    // 16 MiB
    // out_proj split-2 partials: 2 x 16 MiB aliasing ws[0..32 MiB) (dead)
    float*  parts2  = (float*)(ws);

    const int M = BB * LL;  // 2048

    // 0) all f32 -> bf16 conversions + x_proj pad
    k_cvt<<<30208, 256, 0, stream>>>(
        (const float4*)hidden, (const float4*)in_proj, (const float4*)dt_proj_w,
        (const float4*)out_proj, (const float4*)x_proj,
        (us4*)hid_h, (us4*)inp_h, (us4*)dtp_h, (us4*)outp_h, (us4*)xpp);

    // 1) xz = hidden @ in_proj^T   (2048x8192 bf16)
    k_inproj<<<dim3(8192 / 128, M / 128), 256, 0, stream>>>(
        hid_h, DMODEL, inp_h, DMODEL, xz_h, 8192, DMODEL);

    // 2) x_conv = silu(causal_conv(x) + conv_b)
    k_conv<<<(M * DINNER) / 256, 256, 0, stream>>>(xz_h, conv_w, conv_b, xc);

    // 3) x_dbl = x_conv @ x_proj_pad^T  (LDS-free skinny, split-K 4 -> reduce)
    k_xdbl<<<dim3(XDBL_LD / 16, M / 64, 4), 256, 0, stream>>>(
        xc, DINNER, xpp, DINNER, parts, XDBL_LD, DINNER / 4);
    k_xdbl_red<<<131072 / 256, 256, 0, stream>>>(
        (const float4*)parts, (float4*)xdbl, (us4*)xdblh);

    // 4) delta = softplus(dt_lo @ dt_proj_w^T + b)
    k_delta<<<dim3(DINNER / 64, M / 64), 256, 0, stream>>>(
        xdblh, dtp_h, dt_proj_b, delta_h);

    // 5) chunked selective scan + D-skip + silu(z) gating -> y (bf16)
    k_scan1<<<dim3(DINNER / 256, NCH, BB), 256, 0, stream>>>(
        delta_h, xc, xdbl, A_log, Hbuf, sumdt);
    k_scan2<<<(BB * DINNER * DSTATE) / 256, 256, 0, stream>>>(
        A_log, sumdt, Hbuf);
    k_scan3<<<dim3(DINNER / 256, NCH, BB), 256, 0, stream>>>(
        delta_h, xc, xdbl, xz_h, A_log, Dp, Hbuf, yb);

    // 6) out = y @ out_proj^T, K split 2x2048 -> partials -> reduce
    k_outproj<<<dim3(DMODEL / 128, M / 128, 2), 256, 0, stream>>>(
        yb, DINNER, outp_h, DINNER, parts2, DMODEL, DINNER / 2);
    k_out_red<<<1048576 / 256, 256, 0, stream>>>(
        (const float4*)parts2, (float4*)out);
}